// Round 6
// baseline (721.302 us; speedup 1.0000x reference)
//
#include <hip/hip_runtime.h>
#include <hip/hip_bf16.h>

#define DIM    16
#define BATCH  32
#define KL     4
#define NTS    512
#define NC     4
#define NPAR   16
#define DTF    (1.0f/512.0f)
#define BST    40     // bf16 operand row stride (ushort)

using short8  = __attribute__((ext_vector_type(8))) short;
using f32x4   = __attribute__((ext_vector_type(4))) float;
using uintx2  = __attribute__((ext_vector_type(2))) unsigned int;

__device__ __forceinline__ float b2f(__hip_bfloat16 x) { return __bfloat162float(x); }

__device__ __forceinline__ float ldval(const void* p, int idx, bool isf32) {
  return isf32 ? ((const float*)p)[idx]
               : __bfloat162float(((const __hip_bfloat16*)p)[idx]);
}
__device__ __forceinline__ unsigned short f2bf(float x) {   // RNE (setup/L only)
  unsigned u = __float_as_uint(x);
  unsigned r = u + 0x7FFFu + ((u >> 16) & 1u);
  return (unsigned short)(r >> 16);
}
__device__ __forceinline__ float bf2f(unsigned short h) {
  return __uint_as_float(((unsigned)h) << 16);
}
__device__ __forceinline__ short8 ldfrag(const unsigned short* p) {
  return *(const short8*)p;
}
__device__ __forceinline__ short8 negbf8(short8 a) {
  union { short8 s; unsigned u[4]; } v; v.s = a;
  #pragma unroll
  for (int q = 0; q < 4; ++q) v.u[q] ^= 0x80008000u;
  return v.s;
}
// hi/lo 3-product MFMA: order hh + lh + hl (baseline mm3)
__device__ __forceinline__ f32x4 mm3(short8 Ah, short8 Al, short8 Bh, short8 Bl, f32x4 acc) {
  acc = __builtin_amdgcn_mfma_f32_16x16x32_bf16(Ah, Bh, acc, 0, 0, 0);
  acc = __builtin_amdgcn_mfma_f32_16x16x32_bf16(Al, Bh, acc, 0, 0, 0);
  acc = __builtin_amdgcn_mfma_f32_16x16x32_bf16(Ah, Bl, acc, 0, 0, 0);
  return acc;
}
// transpose-mirrored order: hh + hl + lh (R3/R4-verified for M^T)
__device__ __forceinline__ f32x4 mm3b(short8 Ah, short8 Al, short8 Bh, short8 Bl, f32x4 acc) {
  acc = __builtin_amdgcn_mfma_f32_16x16x32_bf16(Ah, Bh, acc, 0, 0, 0);
  acc = __builtin_amdgcn_mfma_f32_16x16x32_bf16(Ah, Bl, acc, 0, 0, 0);
  acc = __builtin_amdgcn_mfma_f32_16x16x32_bf16(Al, Bh, acc, 0, 0, 0);
  return acc;
}
// trunc hi/lo pack of f32x4 -> 2 hi dwords + 2 lo dwords (bit-identical to split2; verified)
__device__ __forceinline__ void pack4d(f32x4 v, unsigned& h0, unsigned& h1,
                                       unsigned& l0, unsigned& l1) {
  unsigned u0 = __float_as_uint(v[0]), u1 = __float_as_uint(v[1]);
  unsigned u2 = __float_as_uint(v[2]), u3 = __float_as_uint(v[3]);
  h0 = __builtin_amdgcn_perm(u1, u0, 0x07060302u);   // [hi(v1)|hi(v0)]  rows 4r+0,1
  h1 = __builtin_amdgcn_perm(u3, u2, 0x07060302u);   // rows 4r+2,3
  float r0 = v[0] - __uint_as_float(u0 & 0xFFFF0000u);
  float r1 = v[1] - __uint_as_float(u1 & 0xFFFF0000u);
  float r2 = v[2] - __uint_as_float(u2 & 0xFFFF0000u);
  float r3 = v[3] - __uint_as_float(u3 & 0xFFFF0000u);
  l0 = __builtin_amdgcn_perm(__float_as_uint(r1), __float_as_uint(r0), 0x07060302u);
  l1 = __builtin_amdgcn_perm(__float_as_uint(r3), __float_as_uint(r2), 0x07060302u);
}
__device__ __forceinline__ void pack8(const float* v, short8& hi, short8& lo) {
  union { short8 s; unsigned d[4]; } H, L;
  #pragma unroll
  for (int j = 0; j < 4; ++j) {
    unsigned ua = __float_as_uint(v[2*j]), ub = __float_as_uint(v[2*j+1]);
    H.d[j] = __builtin_amdgcn_perm(ub, ua, 0x07060302u);
    float ra = v[2*j]   - __uint_as_float(ua & 0xFFFF0000u);
    float rb = v[2*j+1] - __uint_as_float(ub & 0xFFFF0000u);
    L.d[j] = __builtin_amdgcn_perm(__float_as_uint(rb), __float_as_uint(ra), 0x07060302u);
  }
  hi = H.s; lo = L.s;
}
// In-register C-layout -> fragment transpose core (gfx950 permlane swaps).
// Inputs A,B: one dword (row-pair) of the packed C-layout accs of X (A) and Y (B).
// Outputs: p = fragment dword from even-r source lanes (g0/g2), q = from odd (g1/g3).
__device__ __forceinline__ void xpose2(unsigned A, unsigned B, unsigned& p, unsigned& q) {
  uintx2 xy = __builtin_amdgcn_permlane32_swap(A, B, false, false);
  // xy[0]=[A.g0,A.g1,B.g0,B.g1]  xy[1]=[A.g2,A.g3,B.g2,B.g3]
  uintx2 pq = __builtin_amdgcn_permlane16_swap(xy[0], xy[1], false, false);
  // pq[0]=[A.g0,A.g2,B.g0,B.g2]  pq[1]=[A.g1,A.g3,B.g1,B.g3]
  p = pq[0]; q = pq[1];
}
// Build the A/B-fragment of stacked [X;Y] (lane c+16w holds rows 8w..8w+7) from the
// packed C-layout dwords of X and Y. Bit-identical to the LDS round-trip version.
__device__ __forceinline__ void mkfrag(unsigned XH0, unsigned XH1, unsigned XL0, unsigned XL1,
                                       unsigned YH0, unsigned YH1, unsigned YL0, unsigned YL1,
                                       short8& h, short8& l) {
  union { short8 s; unsigned d[4]; } H, L;
  xpose2(XH0, YH0, H.d[0], H.d[2]);   // rows 8w+0,1 and 8w+4,5
  xpose2(XH1, YH1, H.d[1], H.d[3]);   // rows 8w+2,3 and 8w+6,7
  xpose2(XL0, YL0, L.d[0], L.d[2]);
  xpose2(XL1, YL1, L.d[1], L.d[3]);
  h = H.s; l = L.s;
}

// R5: single-wave chain, ZERO LDS in the main loop. All MFMA-layout conversions
// (rho-state->frags, T-acc->T-frag) are in-register permlane32/16_swap transposes
// (bit-identical bytes to the verified LDS round-trips). M/M^T via the R3/R4-verified
// register path. Per step: 60 MFMA + ~330 VALU + 1 broadcast sU read + 1 pops write.
__global__ __launch_bounds__(128, 1)
void lindblad_evolve(const void* __restrict__ g_params,
                     const void* __restrict__ g_H0re, const void* __restrict__ g_H0im,
                     const void* __restrict__ g_Hcre, const void* __restrict__ g_Hcim,
                     const void* __restrict__ g_Lre,  const void* __restrict__ g_Lim,
                     const void* __restrict__ g_r0re, const void* __restrict__ g_r0im,
                     float* __restrict__ g_out)
{
  __shared__ __align__(16) float sG[10*256];                                // G planes
  __shared__ __align__(16) float sU[NTS][NC];
  __shared__ __align__(16) unsigned short sLh[KL][16*BST], sLl[KL][16*BST]; // L'_k hi/lo
  __shared__ __align__(16) float sPops[NTS*DIM];
  __shared__ int sFlag;

  const int tid = threadIdx.x;       // 0..127 (wave1 = setup helper, retires)
  const int b   = blockIdx.x;
  const int wv  = tid >> 6;
  const int ln  = tid & 63;
  const int fm  = ln & 15;
  const int fq  = ln >> 4;
  const int row0 = fq * 4;
  const int fOff  = fm*BST + fq*8;
  const int fOffS = fm*BST + ((fq*8 + 16) & 31);

  // ---- input storage-dtype detection (verified) ----
  if (tid == 0) sFlag = 0;
  __syncthreads();
  for (int e = tid; e < 256; e += 128) {
    float v = b2f(((const __hip_bfloat16*)g_H0re)[e]);
    if (!(fabsf(v) <= 1e10f)) atomicOr(&sFlag, 1);
  }
  __syncthreads();
  const bool isf32 = (sFlag != 0);

  // ---- B-spline control pulses (128 threads: 4 passes) ----
  for (int t0 = tid; t0 < NTS; t0 += 128) {
    float kn[20];
    kn[0] = 0.f; kn[1] = 0.f; kn[2] = 0.f;
    #pragma unroll
    for (int q = 0; q < 14; ++q) kn[3 + q] = (float)q / 13.0f;
    kn[17] = 1.f; kn[18] = 1.f; kn[19] = 1.f;
    const float t = (float)t0 * DTF;
    float B[19];
    #pragma unroll
    for (int q = 0; q < 19; ++q) B[q] = (kn[q] <= t && t < kn[q+1]) ? 1.f : 0.f;
    #pragma unroll
    for (int d = 1; d <= 3; ++d) {
      #pragma unroll
      for (int q = 0; q + d < 19; ++q) {
        float ld = kn[q+d]   - kn[q];
        float rd = kn[q+d+1] - kn[q+1];
        float lv = (ld > 0.f) ? (t - kn[q])     / ld * B[q]   : 0.f;
        float rv = (rd > 0.f) ? (kn[q+d+1] - t) / rd * B[q+1] : 0.f;
        B[q] = lv + rv;
      }
    }
    #pragma unroll
    for (int c = 0; c < NC; ++c) {
      float s = 0.f;
      #pragma unroll
      for (int q = 0; q < NPAR; ++q) s += B[q] * ldval(g_params, q*NC + c, isf32);
      sU[t0][c] = s;
    }
  }

  // ---- constants staging (128 threads: 2 passes, elementwise (i,j)) ----
  for (int e = tid; e < 256; e += 128) {
    const int i = e >> 4, j = e & 15;
    const int ij = i*16 + j, ji = j*16 + i;
    float h0r = 0.5f * (ldval(g_H0re, ij, isf32) + ldval(g_H0re, ji, isf32));
    float h0i = 0.5f * (ldval(g_H0im, ij, isf32) - ldval(g_H0im, ji, isf32));
    float ldr = 0.f, ldi = 0.f;
    for (int k = 0; k < KL; ++k) {
      #pragma unroll
      for (int m = 0; m < DIM; ++m) {
        float ar = ldval(g_Lre, k*256 + m*16 + i, isf32), ai = ldval(g_Lim, k*256 + m*16 + i, isf32);
        float br = ldval(g_Lre, k*256 + m*16 + j, isf32), bi = ldval(g_Lim, k*256 + m*16 + j, isf32);
        ldr += ar*br + ai*bi;
        ldi += ar*bi - ai*br;
      }
    }
    sG[0*256 + ij] =  h0i - 0.5f*ldr;   // G0r
    sG[1*256 + ij] = -h0r - 0.5f*ldi;   // G0i
    #pragma unroll
    for (int c = 0; c < NC; ++c) {
      float hr = 0.5f * (ldval(g_Hcre, c*256 + ij, isf32) + ldval(g_Hcre, c*256 + ji, isf32));
      float hi = 0.5f * (ldval(g_Hcim, c*256 + ij, isf32) - ldval(g_Hcim, c*256 + ji, isf32));
      sG[(2 + 2*c)*256 + ij] =  hi;
      sG[(3 + 2*c)*256 + ij] = -hr;
    }
    // L': RNE hi/lo split
    #pragma unroll
    for (int k = 0; k < KL; ++k) {
      float lr = ldval(g_Lre, k*256 + ij, isf32);
      float li = ldval(g_Lim, k*256 + ij, isf32);
      unsigned short h;
      h = f2bf(lr); sLh[k][i*BST + j]      = h; sLl[k][i*BST + j]      = f2bf(lr - bf2f(h));
      h = f2bf(li); sLh[k][i*BST + 16 + j] = h; sLl[k][i*BST + 16 + j] = f2bf(li - bf2f(h));
    }
  }

  __syncthreads();   // setup visible; last barrier in the kernel
  if (wv != 0) return;   // wave1 retires; wave0 runs the LDS-free loop

  // ---- preloads (all constants into registers; baseline-verbatim indexing) ----
  float G0v[8], Gcv[NC][8];
  {
    const int comp = (fq < 2) ? 0 : 1;
    const int base = (fq & 1) * 8;
    const float* scr = sG;
    {
      const float* s0 = &scr[comp*256 + fm*16 + base];
      f32x4 va = *(const f32x4*)s0, vb = *(const f32x4*)(s0 + 4);
      #pragma unroll
      for (int q = 0; q < 4; ++q) { G0v[q] = va[q]; G0v[4+q] = vb[q]; }
    }
    #pragma unroll
    for (int c = 0; c < NC; ++c) {
      const float* s0 = &scr[(2 + 2*c + comp)*256 + fm*16 + base];
      f32x4 va = *(const f32x4*)s0, vb = *(const f32x4*)(s0 + 4);
      #pragma unroll
      for (int q = 0; q < 4; ++q) { Gcv[c][q] = va[q]; Gcv[c][4+q] = vb[q]; }
    }
  }
  // L-const fragments (R2/R4-verified): LF = straight (T_i's B AND J_r's A);
  // TrB = LF neg fq>=2 (T_r's B); LS = swapped + neg fq<2 (J_i's A).
  short8 LFh[KL], LFl[KL], TrBh[KL], TrBl[KL], LSh[KL], LSl[KL];
  #pragma unroll
  for (int k = 0; k < KL; ++k) {
    LFh[k] = ldfrag(&sLh[k][fOff]);
    LFl[k] = ldfrag(&sLl[k][fOff]);
    TrBh[k] = (fq >= 2) ? negbf8(LFh[k]) : LFh[k];
    TrBl[k] = (fq >= 2) ? negbf8(LFl[k]) : LFl[k];
    short8 h = ldfrag(&sLh[k][fOffS]);
    short8 l = ldfrag(&sLl[k][fOffS]);
    if (fq < 2) { h = negbf8(h); l = negbf8(l); }
    LSh[k] = h; LSl[k] = l;
  }
  // rho C-layout state: lane (fm,fq) owns rho[4fq+q][fm], re and im
  f32x4 rmr, rmi;
  #pragma unroll
  for (int q = 0; q < 4; ++q) {
    rmr[q] = ldval(g_r0re, b*256 + (row0 + q)*16 + fm, isf32);
    rmi[q] = ldval(g_r0im, b*256 + (row0 + q)*16 + fm, isf32);
  }

  const f32x4 zero = {0.f, 0.f, 0.f, 0.f};

  // ---- main Euler loop: single wave, zero barriers, zero LDS round-trips ----
  #pragma unroll 1
  for (int t = 0; t < NTS; ++t) {
    // G(t) A-fragment (baseline-verbatim gv + pack8)
    f32x4 uv = *(const f32x4*)&sU[t][0];
    float gv[8];
    #pragma unroll
    for (int q = 0; q < 8; ++q)
      gv[q] = G0v[q] + uv[0]*Gcv[0][q] + uv[1]*Gcv[1][q] + uv[2]*Gcv[2][q] + uv[3]*Gcv[3][q];
    short8 Ah, Al;
    pack8(gv, Ah, Al);

    // rho fragments via in-register transpose (bytes == old ldfrag(sPh/sPl))
    unsigned RH0, RH1, RL0, RL1, IH0, IH1, IL0, IL1;
    pack4d(rmr, RH0, RH1, RL0, RL1);
    pack4d(rmi, IH0, IH1, IL0, IL1);
    short8 Pfh, Pfl, Psh, Psl;
    mkfrag(RH0, RH1, RL0, RL1, IH0, IH1, IL0, IL1, Pfh, Pfl);  // straight [rho_r^T|rho_i^T]
    mkfrag(IH0, IH1, IL0, IL1, RH0, RH1, RL0, RL1, Psh, Psl);  // swapped  [rho_i^T|rho_r^T]

    // ---- M components in registers (R3/R4-verified) ----
    short8 MBh = (fq >= 2) ? negbf8(Pfh) : Pfh;                // B = [rho_r; -rho_i]
    short8 MBl = (fq >= 2) ? negbf8(Pfl) : Pfl;
    f32x4 mAr  = mm3(Ah, Al, MBh, MBl, zero);                  // Mr[4fq+q][fm]
    short8 Gth = (fq >= 2) ? negbf8(Ah) : Ah;                  // B-frag of [Gr^T; -Gi^T]
    short8 Gtl = (fq >= 2) ? negbf8(Al) : Al;
    f32x4 mtAr = mm3b(Pfh, Pfl, Gth, Gtl, zero);               // Mr^T[4fq+q][fm]
    f32x4 mAi  = mm3(Ah, Al, Psh, Psl, zero);                  // Mi
    f32x4 mtAi = mm3b(Psh, Psl, Ah, Al, zero);                 // Mi^T

    // ---- T_k then J_k, fully in registers (4 independent chains) ----
    f32x4 jr[KL], ji[KL];
    #pragma unroll
    for (int k = 0; k < KL; ++k) {
      f32x4 tr = mm3(Pfh, Pfl, TrBh[k], TrBl[k], zero);        // Tr^T (C-layout)
      f32x4 ti = mm3(Psh, Psl, LFh[k],  LFl[k],  zero);        // Ti^T (C-layout)
      unsigned TH0, TH1, TL0, TL1, UH0, UH1, UL0, UL1;
      pack4d(tr, TH0, TH1, TL0, TL1);
      pack4d(ti, UH0, UH1, UL0, UL1);
      short8 Th, Tl;
      mkfrag(TH0, TH1, TL0, TL1, UH0, UH1, UL0, UL1, Th, Tl);  // B-frag [Tr^T; Ti^T]
      jr[k] = mm3(LFh[k], LFl[k], Th, Tl, zero);               // Jr_k (C-layout)
      ji[k] = mm3(LSh[k], LSl[k], Th, Tl, zero);               // Ji_k (C-layout, = -Ji)
    }

    // ---- Euler update (baseline-verbatim signs and sum tree) ----
    #pragma unroll
    for (int q = 0; q < 4; ++q) {
      rmr[q] += DTF * (mAr[q] + mtAr[q] + ((jr[0][q] + jr[1][q]) + (jr[2][q] + jr[3][q])));
      rmi[q] += DTF * (mAi[q] - mtAi[q] - ((ji[0][q] + ji[1][q]) + (ji[2][q] + ji[3][q])));
    }

    // pops: diagonal of rho_re(t+1) staged to LDS (conflict-free: 16 lanes, 16 banks)
    if ((unsigned)(fm - row0) < 4u) sPops[t*DIM + fm] = rmr[fm - row0];
  }

  // ---- final coalesced pops flush (float4), 64 lanes ----
  for (int i4 = ln; i4 < NTS*DIM/4; i4 += 64) {
    int idx = i4 * 4;                            // idx = t*16 + d, d 4-aligned
    int tt = idx >> 4, dd = idx & 15;
    *(float4*)&g_out[tt*(BATCH*DIM) + b*DIM + dd] = *(const float4*)&sPops[idx];
  }
}

extern "C" void kernel_launch(void* const* d_in, const int* in_sizes, int n_in,
                              void* d_out, int out_size, void* d_ws, size_t ws_size,
                              hipStream_t stream) {
  (void)out_size; (void)d_ws; (void)ws_size;
  const void *P, *H0r, *H0i, *Hcr, *Hci, *Lr, *Li, *R0r, *R0i;
  int idx64 = -1;
  for (int q = 0; q < n_in; ++q) if (in_sizes[q] == 64) idx64 = q;
  if (idx64 == 6) {   // alphabetical fallback
    H0i = d_in[0]; H0r = d_in[1];
    Hci = d_in[2]; Hcr = d_in[3];
    Li  = d_in[4]; Lr  = d_in[5];
    P   = d_in[6];
    R0i = d_in[7]; R0r = d_in[8];
  } else {            // documented setup_inputs() dict order (R4-verified)
    P   = d_in[0];
    H0r = d_in[1]; H0i = d_in[2];
    Hcr = d_in[3]; Hci = d_in[4];
    Lr  = d_in[5]; Li  = d_in[6];
    R0r = d_in[7]; R0i = d_in[8];
  }
  lindblad_evolve<<<dim3(BATCH), dim3(128), 0, stream>>>(
      P, H0r, H0i, Hcr, Hci, Lr, Li, R0r, R0i, (float*)d_out);
}

// Round 7
// 651.192 us; speedup vs baseline: 1.1077x; 1.1077x over previous
//
#include <hip/hip_runtime.h>
#include <hip/hip_bf16.h>

#define DIM    16
#define BATCH  32
#define KL     4
#define NTS    512
#define NC     4
#define NPAR   16
#define DTF    (1.0f/512.0f)
#define BST    40     // bf16 operand row stride (ushort)

using short8  = __attribute__((ext_vector_type(8))) short;
using f32x4   = __attribute__((ext_vector_type(4))) float;
using uintx2  = __attribute__((ext_vector_type(2))) unsigned int;

__device__ __forceinline__ float b2f(__hip_bfloat16 x) { return __bfloat162float(x); }

__device__ __forceinline__ float ldval(const void* p, int idx, bool isf32) {
  return isf32 ? ((const float*)p)[idx]
               : __bfloat162float(((const __hip_bfloat16*)p)[idx]);
}
__device__ __forceinline__ unsigned short f2bf(float x) {   // RNE (setup/L only)
  unsigned u = __float_as_uint(x);
  unsigned r = u + 0x7FFFu + ((u >> 16) & 1u);
  return (unsigned short)(r >> 16);
}
__device__ __forceinline__ float bf2f(unsigned short h) {
  return __uint_as_float(((unsigned)h) << 16);
}
__device__ __forceinline__ short8 ldfrag(const unsigned short* p) {
  return *(const short8*)p;
}
__device__ __forceinline__ short8 negbf8(short8 a) {
  union { short8 s; unsigned u[4]; } v; v.s = a;
  #pragma unroll
  for (int q = 0; q < 4; ++q) v.u[q] ^= 0x80008000u;
  return v.s;
}
// hi/lo 3-product MFMA: order hh + lh + hl (baseline mm3)
__device__ __forceinline__ f32x4 mm3(short8 Ah, short8 Al, short8 Bh, short8 Bl, f32x4 acc) {
  acc = __builtin_amdgcn_mfma_f32_16x16x32_bf16(Ah, Bh, acc, 0, 0, 0);
  acc = __builtin_amdgcn_mfma_f32_16x16x32_bf16(Al, Bh, acc, 0, 0, 0);
  acc = __builtin_amdgcn_mfma_f32_16x16x32_bf16(Ah, Bl, acc, 0, 0, 0);
  return acc;
}
// transpose-mirrored order: hh + hl + lh (R3/R4-verified for M^T)
__device__ __forceinline__ f32x4 mm3b(short8 Ah, short8 Al, short8 Bh, short8 Bl, f32x4 acc) {
  acc = __builtin_amdgcn_mfma_f32_16x16x32_bf16(Ah, Bh, acc, 0, 0, 0);
  acc = __builtin_amdgcn_mfma_f32_16x16x32_bf16(Ah, Bl, acc, 0, 0, 0);
  acc = __builtin_amdgcn_mfma_f32_16x16x32_bf16(Al, Bh, acc, 0, 0, 0);
  return acc;
}
// trunc hi/lo pack of f32x4 -> 2 hi dwords + 2 lo dwords (bit-identical to split2; verified)
__device__ __forceinline__ void pack4d(f32x4 v, unsigned& h0, unsigned& h1,
                                       unsigned& l0, unsigned& l1) {
  unsigned u0 = __float_as_uint(v[0]), u1 = __float_as_uint(v[1]);
  unsigned u2 = __float_as_uint(v[2]), u3 = __float_as_uint(v[3]);
  h0 = __builtin_amdgcn_perm(u1, u0, 0x07060302u);   // [hi(v1)|hi(v0)]  rows 4r+0,1
  h1 = __builtin_amdgcn_perm(u3, u2, 0x07060302u);   // rows 4r+2,3
  float r0 = v[0] - __uint_as_float(u0 & 0xFFFF0000u);
  float r1 = v[1] - __uint_as_float(u1 & 0xFFFF0000u);
  float r2 = v[2] - __uint_as_float(u2 & 0xFFFF0000u);
  float r3 = v[3] - __uint_as_float(u3 & 0xFFFF0000u);
  l0 = __builtin_amdgcn_perm(__float_as_uint(r1), __float_as_uint(r0), 0x07060302u);
  l1 = __builtin_amdgcn_perm(__float_as_uint(r3), __float_as_uint(r2), 0x07060302u);
}
__device__ __forceinline__ void pack8(const float* v, short8& hi, short8& lo) {
  union { short8 s; unsigned d[4]; } H, L;
  #pragma unroll
  for (int j = 0; j < 4; ++j) {
    unsigned ua = __float_as_uint(v[2*j]), ub = __float_as_uint(v[2*j+1]);
    H.d[j] = __builtin_amdgcn_perm(ub, ua, 0x07060302u);
    float ra = v[2*j]   - __uint_as_float(ua & 0xFFFF0000u);
    float rb = v[2*j+1] - __uint_as_float(ub & 0xFFFF0000u);
    L.d[j] = __builtin_amdgcn_perm(__float_as_uint(rb), __float_as_uint(ra), 0x07060302u);
  }
  hi = H.s; lo = L.s;
}
// In-register C-layout -> fragment transpose core (gfx950 permlane swaps; R5-verified)
__device__ __forceinline__ void xpose2(unsigned A, unsigned B, unsigned& p, unsigned& q) {
  uintx2 xy = __builtin_amdgcn_permlane32_swap(A, B, false, false);
  uintx2 pq = __builtin_amdgcn_permlane16_swap(xy[0], xy[1], false, false);
  p = pq[0]; q = pq[1];
}
// Build the A/B-fragment of stacked [X;Y] from packed C-layout dwords (R5-verified bytes)
__device__ __forceinline__ void mkfrag(unsigned XH0, unsigned XH1, unsigned XL0, unsigned XL1,
                                       unsigned YH0, unsigned YH1, unsigned YL0, unsigned YL1,
                                       short8& h, short8& l) {
  union { short8 s; unsigned d[4]; } H, L;
  xpose2(XH0, YH0, H.d[0], H.d[2]);
  xpose2(XH1, YH1, H.d[1], H.d[3]);
  xpose2(XL0, YL0, L.d[0], L.d[2]);
  xpose2(XL1, YL1, L.d[1], L.d[3]);
  h = H.s; l = L.s;
}

// R6: 4 symmetric waves, ONE barrier per step, J-partials = the only loop LDS traffic.
// Every wave holds the full rho state in registers and redundantly computes the update
// with bit-identical f32 ops (waves stay in sync forever; no rho exchange). Wave k owns
// operator k: T_k and J_k via R5-verified in-register permlane transposes; J partial
// exchanged through double-buffered LDS slots (2 writes + 6 reads of b128 per wave).
// M/M^T via the R3/R4-verified register identity, duplicated on all 4 waves.
__global__ __launch_bounds__(256, 1)
void lindblad_evolve(const void* __restrict__ g_params,
                     const void* __restrict__ g_H0re, const void* __restrict__ g_H0im,
                     const void* __restrict__ g_Hcre, const void* __restrict__ g_Hcim,
                     const void* __restrict__ g_Lre,  const void* __restrict__ g_Lim,
                     const void* __restrict__ g_r0re, const void* __restrict__ g_r0im,
                     float* __restrict__ g_out)
{
  __shared__ __align__(16) float sG[10*256];                                // G planes
  __shared__ __align__(16) float sU[NTS][NC];
  __shared__ __align__(16) unsigned short sLh[KL][16*BST], sLl[KL][16*BST]; // L'_k hi/lo
  __shared__ __align__(16) float sJr[2][KL][256], sJi[2][KL][256];          // J partials, dbuf
  __shared__ __align__(16) float sPops[NTS*DIM];
  __shared__ int sFlag;

  const int tid = threadIdx.x;       // 0..255 (4 waves; wave == operator k)
  const int b   = blockIdx.x;
  const int wv  = tid >> 6;
  const int ln  = tid & 63;
  const int fm  = ln & 15;
  const int fq  = ln >> 4;
  const int row0 = fq * 4;
  const int fOff  = fm*BST + fq*8;
  const int fOffS = fm*BST + ((fq*8 + 16) & 31);

  // ---- input storage-dtype detection (verified) ----
  if (tid == 0) sFlag = 0;
  __syncthreads();
  {
    float v = b2f(((const __hip_bfloat16*)g_H0re)[tid]);
    if (!(fabsf(v) <= 1e10f)) atomicOr(&sFlag, 1);
  }
  __syncthreads();
  const bool isf32 = (sFlag != 0);

  // ---- B-spline control pulses (256 threads: 2 passes) ----
  for (int t0 = tid; t0 < NTS; t0 += 256) {
    float kn[20];
    kn[0] = 0.f; kn[1] = 0.f; kn[2] = 0.f;
    #pragma unroll
    for (int q = 0; q < 14; ++q) kn[3 + q] = (float)q / 13.0f;
    kn[17] = 1.f; kn[18] = 1.f; kn[19] = 1.f;
    const float t = (float)t0 * DTF;
    float B[19];
    #pragma unroll
    for (int q = 0; q < 19; ++q) B[q] = (kn[q] <= t && t < kn[q+1]) ? 1.f : 0.f;
    #pragma unroll
    for (int d = 1; d <= 3; ++d) {
      #pragma unroll
      for (int q = 0; q + d < 19; ++q) {
        float ld = kn[q+d]   - kn[q];
        float rd = kn[q+d+1] - kn[q+1];
        float lv = (ld > 0.f) ? (t - kn[q])     / ld * B[q]   : 0.f;
        float rv = (rd > 0.f) ? (kn[q+d+1] - t) / rd * B[q+1] : 0.f;
        B[q] = lv + rv;
      }
    }
    #pragma unroll
    for (int c = 0; c < NC; ++c) {
      float s = 0.f;
      #pragma unroll
      for (int q = 0; q < NPAR; ++q) s += B[q] * ldval(g_params, q*NC + c, isf32);
      sU[t0][c] = s;
    }
  }

  // ---- constants staging (256 threads: 1 pass, elementwise (i,j)) ----
  {
    const int e = tid;
    const int i = e >> 4, j = e & 15;
    const int ij = i*16 + j, ji = j*16 + i;
    float h0r = 0.5f * (ldval(g_H0re, ij, isf32) + ldval(g_H0re, ji, isf32));
    float h0i = 0.5f * (ldval(g_H0im, ij, isf32) - ldval(g_H0im, ji, isf32));
    float ldr = 0.f, ldi = 0.f;
    for (int k = 0; k < KL; ++k) {
      #pragma unroll
      for (int m = 0; m < DIM; ++m) {
        float ar = ldval(g_Lre, k*256 + m*16 + i, isf32), ai = ldval(g_Lim, k*256 + m*16 + i, isf32);
        float br = ldval(g_Lre, k*256 + m*16 + j, isf32), bi = ldval(g_Lim, k*256 + m*16 + j, isf32);
        ldr += ar*br + ai*bi;
        ldi += ar*bi - ai*br;
      }
    }
    sG[0*256 + ij] =  h0i - 0.5f*ldr;   // G0r
    sG[1*256 + ij] = -h0r - 0.5f*ldi;   // G0i
    #pragma unroll
    for (int c = 0; c < NC; ++c) {
      float hr = 0.5f * (ldval(g_Hcre, c*256 + ij, isf32) + ldval(g_Hcre, c*256 + ji, isf32));
      float hi = 0.5f * (ldval(g_Hcim, c*256 + ij, isf32) - ldval(g_Hcim, c*256 + ji, isf32));
      sG[(2 + 2*c)*256 + ij] =  hi;
      sG[(3 + 2*c)*256 + ij] = -hr;
    }
    // L': RNE hi/lo split
    #pragma unroll
    for (int k = 0; k < KL; ++k) {
      float lr = ldval(g_Lre, k*256 + ij, isf32);
      float li = ldval(g_Lim, k*256 + ij, isf32);
      unsigned short h;
      h = f2bf(lr); sLh[k][i*BST + j]      = h; sLl[k][i*BST + j]      = f2bf(lr - bf2f(h));
      h = f2bf(li); sLh[k][i*BST + 16 + j] = h; sLl[k][i*BST + 16 + j] = f2bf(li - bf2f(h));
    }
  }

  __syncthreads();   // setup visible

  // ---- per-wave preloads (baseline-verbatim indexing) ----
  float G0v[8], Gcv[NC][8];
  {
    const int comp = (fq < 2) ? 0 : 1;
    const int base = (fq & 1) * 8;
    const float* scr = sG;
    {
      const float* s0 = &scr[comp*256 + fm*16 + base];
      f32x4 va = *(const f32x4*)s0, vb = *(const f32x4*)(s0 + 4);
      #pragma unroll
      for (int q = 0; q < 4; ++q) { G0v[q] = va[q]; G0v[4+q] = vb[q]; }
    }
    #pragma unroll
    for (int c = 0; c < NC; ++c) {
      const float* s0 = &scr[(2 + 2*c + comp)*256 + fm*16 + base];
      f32x4 va = *(const f32x4*)s0, vb = *(const f32x4*)(s0 + 4);
      #pragma unroll
      for (int q = 0; q < 4; ++q) { Gcv[c][q] = va[q]; Gcv[c][4+q] = vb[q]; }
    }
  }
  // Own-k L-const fragments (R2/R4/R5-verified contents)
  const int k = wv;
  short8 LFh = ldfrag(&sLh[k][fOff]);              // straight: Ti's B AND Jr's A
  short8 LFl = ldfrag(&sLl[k][fOff]);
  short8 TrBh = (fq >= 2) ? negbf8(LFh) : LFh;     // Tr's B
  short8 TrBl = (fq >= 2) ? negbf8(LFl) : LFl;
  short8 LSh, LSl;                                 // Ji's A: swap + neg fq<2
  {
    short8 h = ldfrag(&sLh[k][fOffS]);
    short8 l = ldfrag(&sLl[k][fOffS]);
    if (fq < 2) { h = negbf8(h); l = negbf8(l); }
    LSh = h; LSl = l;
  }
  // rho C-layout state: lane (fm,fq) owns rho[4fq+q][fm] (identical in all waves)
  f32x4 rmr, rmi;
  #pragma unroll
  for (int q = 0; q < 4; ++q) {
    rmr[q] = ldval(g_r0re, b*256 + (row0 + q)*16 + fm, isf32);
    rmi[q] = ldval(g_r0im, b*256 + (row0 + q)*16 + fm, isf32);
  }
  // G(0) A-fragment
  short8 Ah, Al;
  {
    f32x4 uv = *(const f32x4*)&sU[0][0];
    float gv[8];
    #pragma unroll
    for (int q = 0; q < 8; ++q)
      gv[q] = G0v[q] + uv[0]*Gcv[0][q] + uv[1]*Gcv[1][q] + uv[2]*Gcv[2][q] + uv[3]*Gcv[3][q];
    pack8(gv, Ah, Al);
  }

  const f32x4 zero = {0.f, 0.f, 0.f, 0.f};

  // ---- main Euler loop: 4 symmetric waves, 1 barrier/step ----
  #pragma unroll 1
  for (int t = 0; t < NTS; ++t) {
    // rho fragments via in-register transpose (R5-verified bytes)
    unsigned RH0, RH1, RL0, RL1, IH0, IH1, IL0, IL1;
    pack4d(rmr, RH0, RH1, RL0, RL1);
    pack4d(rmi, IH0, IH1, IL0, IL1);
    short8 Pfh, Pfl, Psh, Psl;
    mkfrag(RH0, RH1, RL0, RL1, IH0, IH1, IL0, IL1, Pfh, Pfl);  // [rho_r^T|rho_i^T]
    mkfrag(IH0, IH1, IL0, IL1, RH0, RH1, RL0, RL1, Psh, Psl);  // [rho_i^T|rho_r^T]

    // ---- M components in registers (R3/R4-verified), duplicated on all waves ----
    short8 MBh = (fq >= 2) ? negbf8(Pfh) : Pfh;
    short8 MBl = (fq >= 2) ? negbf8(Pfl) : Pfl;
    f32x4 mAr  = mm3(Ah, Al, MBh, MBl, zero);                  // Mr[4fq+q][fm]
    short8 Gth = (fq >= 2) ? negbf8(Ah) : Ah;
    short8 Gtl = (fq >= 2) ? negbf8(Al) : Al;
    f32x4 mtAr = mm3b(Pfh, Pfl, Gth, Gtl, zero);               // Mr^T
    f32x4 mAi  = mm3(Ah, Al, Psh, Psl, zero);                  // Mi
    f32x4 mtAi = mm3b(Psh, Psl, Ah, Al, zero);                 // Mi^T

    // ---- own T_k then J_k in registers ----
    f32x4 tr = mm3(Pfh, Pfl, TrBh, TrBl, zero);                // Tr^T (C-layout)
    f32x4 ti = mm3(Psh, Psl, LFh,  LFl,  zero);                // Ti^T (C-layout)
    unsigned TH0, TH1, TL0, TL1, UH0, UH1, UL0, UL1;
    pack4d(tr, TH0, TH1, TL0, TL1);
    pack4d(ti, UH0, UH1, UL0, UL1);
    short8 Th, Tl;
    mkfrag(TH0, TH1, TL0, TL1, UH0, UH1, UL0, UL1, Th, Tl);    // B-frag [Tr^T; Ti^T]
    f32x4 jrO = mm3(LFh, LFl, Th, Tl, zero);                   // Jr_k (C-layout)
    f32x4 jiO = mm3(LSh, LSl, Th, Tl, zero);                   // Ji_k (C-layout, = -Ji)

    // ---- exchange J partials (double-buffered; the ONLY loop LDS traffic) ----
    const int p = t & 1;
    *(f32x4*)&sJr[p][k][ln*4] = jrO;
    *(f32x4*)&sJi[p][k][ln*4] = jiO;
    __syncthreads();
    f32x4 jr[KL], ji[KL];
    #pragma unroll
    for (int m = 0; m < KL; ++m) {
      if (m == k) { jr[m] = jrO; ji[m] = jiO; }
      else {
        jr[m] = *(const f32x4*)&sJr[p][m][ln*4];
        ji[m] = *(const f32x4*)&sJi[p][m][ln*4];
      }
    }

    // ---- Euler update (baseline-verbatim signs and sum tree; identical in all waves) ----
    #pragma unroll
    for (int q = 0; q < 4; ++q) {
      rmr[q] += DTF * (mAr[q] + mtAr[q] + ((jr[0][q] + jr[1][q]) + (jr[2][q] + jr[3][q])));
      rmi[q] += DTF * (mAi[q] - mtAi[q] - ((ji[0][q] + ji[1][q]) + (ji[2][q] + ji[3][q])));
    }

    // pops: diagonal of rho_re(t+1) (wave 0 only)
    if (wv == 0 && (unsigned)(fm - row0) < 4u) sPops[t*DIM + fm] = rmr[fm - row0];

    // G(t+1) A-fragment (registers only)
    const int tn = (t + 1 < NTS) ? (t + 1) : t;
    f32x4 uv = *(const f32x4*)&sU[tn][0];
    float gv[8];
    #pragma unroll
    for (int q = 0; q < 8; ++q)
      gv[q] = G0v[q] + uv[0]*Gcv[0][q] + uv[1]*Gcv[1][q] + uv[2]*Gcv[2][q] + uv[3]*Gcv[3][q];
    pack8(gv, Ah, Al);
  }

  // ---- final coalesced pops flush (float4), 256 threads strided ----
  __syncthreads();
  #pragma unroll
  for (int s = 0; s < NTS*DIM/(256*4); ++s) {
    int idx = (s*256 + tid) * 4;                 // idx = t*16 + d, d 4-aligned
    int tt = idx >> 4, dd = idx & 15;
    *(float4*)&g_out[tt*(BATCH*DIM) + b*DIM + dd] = *(const float4*)&sPops[idx];
  }
}

extern "C" void kernel_launch(void* const* d_in, const int* in_sizes, int n_in,
                              void* d_out, int out_size, void* d_ws, size_t ws_size,
                              hipStream_t stream) {
  (void)out_size; (void)d_ws; (void)ws_size;
  const void *P, *H0r, *H0i, *Hcr, *Hci, *Lr, *Li, *R0r, *R0i;
  int idx64 = -1;
  for (int q = 0; q < n_in; ++q) if (in_sizes[q] == 64) idx64 = q;
  if (idx64 == 6) {   // alphabetical fallback
    H0i = d_in[0]; H0r = d_in[1];
    Hci = d_in[2]; Hcr = d_in[3];
    Li  = d_in[4]; Lr  = d_in[5];
    P   = d_in[6];
    R0i = d_in[7]; R0r = d_in[8];
  } else {            // documented setup_inputs() dict order (R4-verified)
    P   = d_in[0];
    H0r = d_in[1]; H0i = d_in[2];
    Hcr = d_in[3]; Hci = d_in[4];
    Lr  = d_in[5]; Li  = d_in[6];
    R0r = d_in[7]; R0i = d_in[8];
  }
  lindblad_evolve<<<dim3(BATCH), dim3(256), 0, stream>>>(
      P, H0r, H0i, Hcr, Hci, Lr, Li, R0r, R0i, (float*)d_out);
}

// Round 8
// 426.396 us; speedup vs baseline: 1.6916x; 1.5272x over previous
//
#include <hip/hip_runtime.h>
#include <hip/hip_bf16.h>

#define DIM    16
#define BATCH  32
#define KL     4
#define NTS    512
#define NC     4
#define NPAR   16
#define DTF    (1.0f/512.0f)
#define BST    40     // bf16 operand row stride (ushort)

using short8  = __attribute__((ext_vector_type(8))) short;
using short4v = __attribute__((ext_vector_type(4))) short;
using f32x4   = __attribute__((ext_vector_type(4))) float;
using uintx2  = __attribute__((ext_vector_type(2))) unsigned int;

__device__ __forceinline__ float b2f(__hip_bfloat16 x) { return __bfloat162float(x); }

__device__ __forceinline__ float ldval(const void* p, int idx, bool isf32) {
  return isf32 ? ((const float*)p)[idx]
               : __bfloat162float(((const __hip_bfloat16*)p)[idx]);
}
__device__ __forceinline__ unsigned short f2bf(float x) {   // RNE (setup/L only)
  unsigned u = __float_as_uint(x);
  unsigned r = u + 0x7FFFu + ((u >> 16) & 1u);
  return (unsigned short)(r >> 16);
}
__device__ __forceinline__ float bf2f(unsigned short h) {
  return __uint_as_float(((unsigned)h) << 16);
}
// trunc-trunc hi/lo split (verified)
__device__ __forceinline__ void split2(float v, unsigned short& h, unsigned short& l) {
  unsigned u = __float_as_uint(v);
  h = (unsigned short)(u >> 16);
  float r = v - __uint_as_float(u & 0xFFFF0000u);
  l = (unsigned short)(__float_as_uint(r) >> 16);
}
__device__ __forceinline__ short8 ldfrag(const unsigned short* p) {
  return *(const short8*)p;
}
__device__ __forceinline__ short8 negbf8(short8 a) {
  union { short8 s; unsigned u[4]; } v; v.s = a;
  #pragma unroll
  for (int q = 0; q < 4; ++q) v.u[q] ^= 0x80008000u;
  return v.s;
}
// hi/lo 3-product, SEPARATE accumulators (latency: 1 MFMA instead of 3 dependent).
// Sum order (hh + lh) + hl matches the sequential mm3 accumulation order.
__device__ __forceinline__ f32x4 mm3s(short8 Ah, short8 Al, short8 Bh, short8 Bl) {
  const f32x4 z = {0.f, 0.f, 0.f, 0.f};
  f32x4 a = __builtin_amdgcn_mfma_f32_16x16x32_bf16(Ah, Bh, z, 0, 0, 0);
  f32x4 b = __builtin_amdgcn_mfma_f32_16x16x32_bf16(Al, Bh, z, 0, 0, 0);
  f32x4 c = __builtin_amdgcn_mfma_f32_16x16x32_bf16(Ah, Bl, z, 0, 0, 0);
  return (a + b) + c;
}
// transpose-mirrored order: (hh + hl) + lh (matches R3/R4-verified mm3b order)
__device__ __forceinline__ f32x4 mm3bs(short8 Ah, short8 Al, short8 Bh, short8 Bl) {
  const f32x4 z = {0.f, 0.f, 0.f, 0.f};
  f32x4 a = __builtin_amdgcn_mfma_f32_16x16x32_bf16(Ah, Bh, z, 0, 0, 0);
  f32x4 b = __builtin_amdgcn_mfma_f32_16x16x32_bf16(Ah, Bl, z, 0, 0, 0);
  f32x4 c = __builtin_amdgcn_mfma_f32_16x16x32_bf16(Al, Bh, z, 0, 0, 0);
  return (a + b) + c;
}
// trunc hi/lo pack of f32x4 via v_perm_b32 — bit-identical to split2 (verified)
__device__ __forceinline__ void pack4(f32x4 v, short4v& hi, short4v& lo) {
  union { short4v s; unsigned d[2]; } H, L;
  unsigned u0 = __float_as_uint(v[0]), u1 = __float_as_uint(v[1]);
  unsigned u2 = __float_as_uint(v[2]), u3 = __float_as_uint(v[3]);
  H.d[0] = __builtin_amdgcn_perm(u1, u0, 0x07060302u);
  H.d[1] = __builtin_amdgcn_perm(u3, u2, 0x07060302u);
  float r0 = v[0] - __uint_as_float(u0 & 0xFFFF0000u);
  float r1 = v[1] - __uint_as_float(u1 & 0xFFFF0000u);
  float r2 = v[2] - __uint_as_float(u2 & 0xFFFF0000u);
  float r3 = v[3] - __uint_as_float(u3 & 0xFFFF0000u);
  L.d[0] = __builtin_amdgcn_perm(__float_as_uint(r1), __float_as_uint(r0), 0x07060302u);
  L.d[1] = __builtin_amdgcn_perm(__float_as_uint(r3), __float_as_uint(r2), 0x07060302u);
  hi = H.s; lo = L.s;
}
// trunc hi/lo pack of f32x4 -> 2 hi dwords + 2 lo dwords (R5/R6-verified bytes)
__device__ __forceinline__ void pack4d(f32x4 v, unsigned& h0, unsigned& h1,
                                       unsigned& l0, unsigned& l1) {
  unsigned u0 = __float_as_uint(v[0]), u1 = __float_as_uint(v[1]);
  unsigned u2 = __float_as_uint(v[2]), u3 = __float_as_uint(v[3]);
  h0 = __builtin_amdgcn_perm(u1, u0, 0x07060302u);
  h1 = __builtin_amdgcn_perm(u3, u2, 0x07060302u);
  float r0 = v[0] - __uint_as_float(u0 & 0xFFFF0000u);
  float r1 = v[1] - __uint_as_float(u1 & 0xFFFF0000u);
  float r2 = v[2] - __uint_as_float(u2 & 0xFFFF0000u);
  float r3 = v[3] - __uint_as_float(u3 & 0xFFFF0000u);
  l0 = __builtin_amdgcn_perm(__float_as_uint(r1), __float_as_uint(r0), 0x07060302u);
  l1 = __builtin_amdgcn_perm(__float_as_uint(r3), __float_as_uint(r2), 0x07060302u);
}
__device__ __forceinline__ void pack8(const float* v, short8& hi, short8& lo) {
  union { short8 s; unsigned d[4]; } H, L;
  #pragma unroll
  for (int j = 0; j < 4; ++j) {
    unsigned ua = __float_as_uint(v[2*j]), ub = __float_as_uint(v[2*j+1]);
    H.d[j] = __builtin_amdgcn_perm(ub, ua, 0x07060302u);
    float ra = v[2*j]   - __uint_as_float(ua & 0xFFFF0000u);
    float rb = v[2*j+1] - __uint_as_float(ub & 0xFFFF0000u);
    L.d[j] = __builtin_amdgcn_perm(__float_as_uint(rb), __float_as_uint(ra), 0x07060302u);
  }
  hi = H.s; lo = L.s;
}
// In-register C-layout -> fragment transpose (gfx950 permlane swaps; R5/R6-verified)
__device__ __forceinline__ void xpose2(unsigned A, unsigned B, unsigned& p, unsigned& q) {
  uintx2 xy = __builtin_amdgcn_permlane32_swap(A, B, false, false);
  uintx2 pq = __builtin_amdgcn_permlane16_swap(xy[0], xy[1], false, false);
  p = pq[0]; q = pq[1];
}
// Build the B-fragment of stacked [X;Y] from packed C-layout dwords (R5/R6-verified bytes)
__device__ __forceinline__ void mkfrag(unsigned XH0, unsigned XH1, unsigned XL0, unsigned XL1,
                                       unsigned YH0, unsigned YH1, unsigned YL0, unsigned YL1,
                                       short8& h, short8& l) {
  union { short8 s; unsigned d[4]; } H, L;
  xpose2(XH0, YH0, H.d[0], H.d[2]);
  xpose2(XH1, YH1, H.d[1], H.d[3]);
  xpose2(XL0, YL0, L.d[0], L.d[2]);
  xpose2(XL1, YL1, L.d[1], L.d[3]);
  h = H.s; l = L.s;
}

// R7 = R4 (tied-best 355us) with two critical-path cuts:
//   (a) all hi/lo triples use SEPARATE-accumulator MFMAs (mm3s/mm3bs) — dependent-MFMA
//       chain per matmul stage drops 3L -> L;
//   (b) the k-wave's T->J fragment conversion uses the R5/R6-verified in-register
//       permlane transpose (pack4d+mkfrag) instead of the same-wave LDS round-trip —
//       sTh/sTl deleted, ~130cy read-back off the phase-1 pole.
// Structure (6 waves, k-parallel, J-slot exchange, G-tile pipelined on wv0's idle
// phase-2 slot, M in registers on update waves) is R4-verbatim. 2 barriers/step.
__global__ __launch_bounds__(384, 1)
void lindblad_evolve(const void* __restrict__ g_params,
                     const void* __restrict__ g_H0re, const void* __restrict__ g_H0im,
                     const void* __restrict__ g_Hcre, const void* __restrict__ g_Hcim,
                     const void* __restrict__ g_Lre,  const void* __restrict__ g_Lim,
                     const void* __restrict__ g_r0re, const void* __restrict__ g_r0im,
                     float* __restrict__ g_out)
{
  __shared__ __align__(16) unsigned short sPh[16*BST], sPl[16*BST];         // rho^T' hi/lo
  __shared__ __align__(16) unsigned short sLh[KL][16*BST], sLl[KL][16*BST]; // L'_k
  __shared__ __align__(16) unsigned short sGh[16*BST], sGl[16*BST];         // G(t) frag tile hi/lo
  __shared__ __align__(16) float sJr[KL][256], sJi[KL][256];                // J_k partials, lane slots
  __shared__ __align__(16) float sU[NTS][NC];
  __shared__ __align__(16) float sPops[NTS*DIM];  // pops; first 2560 f32 = setup G-scratch
  __shared__ int sFlag;

  const int tid = threadIdx.x;       // 0..383 (6 waves)
  const int b   = blockIdx.x;
  const int wv  = tid >> 6;          // 0-3: k-waves | 4: re-update | 5: im-update
  const int ln  = tid & 63;
  const int fm  = ln & 15;
  const int fq  = ln >> 4;
  const int row0 = fq * 4;
  const int fOff  = fm*BST + fq*8;
  const int fOffS = fm*BST + ((fq*8 + 16) & 31);

  // ---- input storage-dtype detection (verified) ----
  if (tid == 0) sFlag = 0;
  __syncthreads();
  if (tid < 256) {
    float v = b2f(((const __hip_bfloat16*)g_H0re)[tid]);
    if (!(fabsf(v) <= 1e10f)) atomicOr(&sFlag, 1);
  }
  __syncthreads();
  const bool isf32 = (sFlag != 0);

  // ---- B-spline control pulses (384 threads, strided) ----
  for (int t0 = tid; t0 < NTS; t0 += 384) {
    float kn[20];
    kn[0] = 0.f; kn[1] = 0.f; kn[2] = 0.f;
    #pragma unroll
    for (int q = 0; q < 14; ++q) kn[3 + q] = (float)q / 13.0f;
    kn[17] = 1.f; kn[18] = 1.f; kn[19] = 1.f;
    const float t = (float)t0 * DTF;
    float B[19];
    #pragma unroll
    for (int q = 0; q < 19; ++q) B[q] = (kn[q] <= t && t < kn[q+1]) ? 1.f : 0.f;
    #pragma unroll
    for (int d = 1; d <= 3; ++d) {
      #pragma unroll
      for (int q = 0; q + d < 19; ++q) {
        float ld = kn[q+d]   - kn[q];
        float rd = kn[q+d+1] - kn[q+1];
        float lv = (ld > 0.f) ? (t - kn[q])     / ld * B[q]   : 0.f;
        float rv = (rd > 0.f) ? (kn[q+d+1] - t) / rd * B[q+1] : 0.f;
        B[q] = lv + rv;
      }
    }
    #pragma unroll
    for (int c = 0; c < NC; ++c) {
      float s = 0.f;
      #pragma unroll
      for (int q = 0; q < NPAR; ++q) s += B[q] * ldval(g_params, q*NC + c, isf32);
      sU[t0][c] = s;
    }
  }

  // ---- constants staging (threads 0..255, elementwise (i,j)) ----
  if (tid < 256) {
    float* scr = sPops;   // planes: 0=G0r 1=G0i 2+2c=Gc_r 3+2c=Gc_i
    const int i = tid >> 4, j = tid & 15;
    const int ij = i*16 + j, ji = j*16 + i;
    float h0r = 0.5f * (ldval(g_H0re, ij, isf32) + ldval(g_H0re, ji, isf32));
    float h0i = 0.5f * (ldval(g_H0im, ij, isf32) - ldval(g_H0im, ji, isf32));
    float ldr = 0.f, ldi = 0.f;
    for (int k = 0; k < KL; ++k) {
      #pragma unroll
      for (int m = 0; m < DIM; ++m) {
        float ar = ldval(g_Lre, k*256 + m*16 + i, isf32), ai = ldval(g_Lim, k*256 + m*16 + i, isf32);
        float br = ldval(g_Lre, k*256 + m*16 + j, isf32), bi = ldval(g_Lim, k*256 + m*16 + j, isf32);
        ldr += ar*br + ai*bi;
        ldi += ar*bi - ai*br;
      }
    }
    scr[0*256 + ij] =  h0i - 0.5f*ldr;   // G0r
    scr[1*256 + ij] = -h0r - 0.5f*ldi;   // G0i
    #pragma unroll
    for (int c = 0; c < NC; ++c) {
      float hr = 0.5f * (ldval(g_Hcre, c*256 + ij, isf32) + ldval(g_Hcre, c*256 + ji, isf32));
      float hi = 0.5f * (ldval(g_Hcim, c*256 + ij, isf32) - ldval(g_Hcim, c*256 + ji, isf32));
      scr[(2 + 2*c)*256 + ij] =  hi;
      scr[(3 + 2*c)*256 + ij] = -hr;
    }
    // L': RNE hi/lo split
    #pragma unroll
    for (int k = 0; k < KL; ++k) {
      float lr = ldval(g_Lre, k*256 + ij, isf32);
      float li = ldval(g_Lim, k*256 + ij, isf32);
      unsigned short h;
      h = f2bf(lr); sLh[k][i*BST + j]      = h; sLl[k][i*BST + j]      = f2bf(lr - bf2f(h));
      h = f2bf(li); sLh[k][i*BST + 16 + j] = h; sLl[k][i*BST + 16 + j] = f2bf(li - bf2f(h));
    }
    // rho^T'(0)
    float r0 = ldval(g_r0re, b*256 + ij, isf32);
    float m0 = ldval(g_r0im, b*256 + ij, isf32);
    unsigned short h, l;
    split2(r0, h, l); sPh[j*BST + i]      = h; sPl[j*BST + i]      = l;
    split2(m0, h, l); sPh[j*BST + 16 + i] = h; sPl[j*BST + 16 + i] = l;
  }

  __syncthreads();   // scratch, sL, sP, sU visible

  // ---- per-wave preloads ----
  short8 LFh_, LFl_, TrBh_, TrBl_, LSh_, LSl_;   // k-waves: L-derived constant frags
  float  G0v[8], Gcv[NC][8];                     // wv0 only (G-rebuild owner)
  float  rm[4] = {0.f,0.f,0.f,0.f};              // wv4: rho_re; wv5: rho_im (C-layout)

  if (wv < 4) {
    const int k = wv;
    LFh_ = ldfrag(&sLh[k][fOff]);                // straight frag: Ti's B AND Jr's A
    LFl_ = ldfrag(&sLl[k][fOff]);
    TrBh_ = (fq >= 2) ? negbf8(LFh_) : LFh_;     // Tr's B
    TrBl_ = (fq >= 2) ? negbf8(LFl_) : LFl_;
    short8 h = ldfrag(&sLh[k][fOffS]);           // Ji's A: swap+neg
    short8 l = ldfrag(&sLl[k][fOffS]);
    if (fq < 2) { h = negbf8(h); l = negbf8(l); }
    LSh_ = h; LSl_ = l;
    if (wv == 0) {
      // G plane windows (baseline preload, verbatim)
      const int comp = (fq < 2) ? 0 : 1;
      const int base = (fq & 1) * 8;
      const float* scr = sPops;
      {
        const float* s0 = &scr[comp*256 + fm*16 + base];
        f32x4 va = *(const f32x4*)s0, vb = *(const f32x4*)(s0 + 4);
        #pragma unroll
        for (int q = 0; q < 4; ++q) { G0v[q] = va[q]; G0v[4+q] = vb[q]; }
      }
      #pragma unroll
      for (int c = 0; c < NC; ++c) {
        const float* s0 = &scr[(2 + 2*c + comp)*256 + fm*16 + base];
        f32x4 va = *(const f32x4*)s0, vb = *(const f32x4*)(s0 + 4);
        #pragma unroll
        for (int q = 0; q < 4; ++q) { Gcv[c][q] = va[q]; Gcv[c][4+q] = vb[q]; }
      }
      // G(0) fragment tile into LDS (same bytes as the in-register pack8)
      f32x4 uv = *(const f32x4*)&sU[0][0];
      float gv[8];
      #pragma unroll
      for (int q = 0; q < 8; ++q)
        gv[q] = G0v[q] + uv[0]*Gcv[0][q] + uv[1]*Gcv[1][q] + uv[2]*Gcv[2][q] + uv[3]*Gcv[3][q];
      short8 Gh_, Gl_;
      pack8(gv, Gh_, Gl_);
      *(short8*)&sGh[fm*BST + fq*8] = Gh_;
      *(short8*)&sGl[fm*BST + fq*8] = Gl_;
    }
  } else if (wv == 4) {
    #pragma unroll
    for (int q = 0; q < 4; ++q) rm[q] = ldval(g_r0re, b*256 + (row0+q)*16 + fm, isf32);
  } else {
    #pragma unroll
    for (int q = 0; q < 4; ++q) rm[q] = ldval(g_r0im, b*256 + (row0+q)*16 + fm, isf32);
  }

  // ---- main Euler loop: 2 barriers/step, 6 waves ----
  #pragma unroll 1
  for (int t = 0; t < NTS; ++t) {
    f32x4 mAcc, mtAcc;   // wv4: Mr, Mr^T; wv5: Mi, Mi^T (own C-layout elements)

    __syncthreads();   // B1: sP(t) + sG(t) visible

    if (wv < 4) {
      // ---- T_k then J_k; fragment conversion fully in registers (R5/R6-verified) ----
      const int k = wv;
      short8 Arh = ldfrag(&sPh[fOff]),  Arl = ldfrag(&sPl[fOff]);    // [rho_r^T|rho_i^T]
      short8 Aih = ldfrag(&sPh[fOffS]), Ail = ldfrag(&sPl[fOffS]);   // [rho_i^T|rho_r^T]
      f32x4 tr = mm3s(Arh, Arl, TrBh_, TrBl_);    // Tr^T tile (C-layout)
      f32x4 ti = mm3s(Aih, Ail, LFh_,  LFl_);     // Ti^T tile (C-layout)
      unsigned TH0, TH1, TL0, TL1, UH0, UH1, UL0, UL1;
      pack4d(tr, TH0, TH1, TL0, TL1);
      pack4d(ti, UH0, UH1, UL0, UL1);
      short8 Th, Tl;
      mkfrag(TH0, TH1, TL0, TL1, UH0, UH1, UL0, UL1, Th, Tl);  // B-frag [Tr^T; Ti^T]
      f32x4 jr = mm3s(LFh_, LFl_, Th, Tl);        // Jr_k contribution (C-layout)
      f32x4 ji = mm3s(LSh_, LSl_, Th, Tl);        // Ji_k contribution (C-layout)
      *(f32x4*)&sJr[k][ln*4] = jr;                // lane-aligned slot, no transpose
      *(f32x4*)&sJi[k][ln*4] = ji;
    } else if (wv == 4) {
      // ---- Mr and Mr^T in registers (R3/R4-verified; G-frag from LDS tile) ----
      short8 Ah = ldfrag(&sGh[fOff]), Al = ldfrag(&sGl[fOff]);
      short8 Ph = ldfrag(&sPh[fOff]), Pl = ldfrag(&sPl[fOff]);       // [rho_r^T|rho_i^T]
      short8 Bh = (fq >= 2) ? negbf8(Ph) : Ph;                       // B = [rho_r; -rho_i]
      short8 Bl = (fq >= 2) ? negbf8(Pl) : Pl;
      mAcc = mm3s(Ah, Al, Bh, Bl);                                   // Mr[4fq+q][fm]
      short8 Gth = (fq >= 2) ? negbf8(Ah) : Ah;                      // B-frag of [Gr^T; -Gi^T]
      short8 Gtl = (fq >= 2) ? negbf8(Al) : Al;
      mtAcc = mm3bs(Ph, Pl, Gth, Gtl);                               // Mr^T[4fq+q][fm]
    } else {
      // ---- Mi and Mi^T in registers (R3/R4-verified) ----
      short8 Ah = ldfrag(&sGh[fOff]), Al = ldfrag(&sGl[fOff]);
      short8 Ph = ldfrag(&sPh[fOffS]), Pl = ldfrag(&sPl[fOffS]);     // [rho_i^T|rho_r^T]
      mAcc = mm3s(Ah, Al, Ph, Pl);                                   // Mi[4fq+q][fm]
      mtAcc = mm3bs(Ph, Pl, Ah, Al);                                 // Mi^T[4fq+q][fm]
    }

    __syncthreads();   // B2: sJ visible

    if (wv >= 4) {
      // ---- update: read J partials (slot copy), tree-sum, Euler, pack, write rho ----
      const float* sJ = (wv == 4) ? &sJr[0][0] : &sJi[0][0];
      f32x4 a0 = *(const f32x4*)&sJ[0*256 + ln*4];
      f32x4 a1 = *(const f32x4*)&sJ[1*256 + ln*4];
      f32x4 a2 = *(const f32x4*)&sJ[2*256 + ln*4];
      f32x4 a3 = *(const f32x4*)&sJ[3*256 + ln*4];
      short4v HH, LL;
      f32x4 rv;
      if (wv == 4) {
        #pragma unroll
        for (int q = 0; q < 4; ++q) {
          rm[q] += DTF * (mAcc[q] + mtAcc[q] + ((a0[q] + a1[q]) + (a2[q] + a3[q])));
          rv[q] = rm[q];
        }
        pack4(rv, HH, LL);
        *(short4v*)&sPh[fm*BST + row0] = HH;
        *(short4v*)&sPl[fm*BST + row0] = LL;
        if ((unsigned)(fm - row0) < 4u) sPops[t*DIM + fm] = rm[fm - row0];
      } else {
        #pragma unroll
        for (int q = 0; q < 4; ++q) {
          // Ji^T = -Ji at own element -> subtract; -Mi^T from mtAcc
          rm[q] += DTF * (mAcc[q] - mtAcc[q] - ((a0[q] + a1[q]) + (a2[q] + a3[q])));
          rv[q] = rm[q];
        }
        pack4(rv, HH, LL);
        *(short4v*)&sPh[fm*BST + 16 + row0] = HH;
        *(short4v*)&sPl[fm*BST + 16 + row0] = LL;
      }
    } else if (wv == 0) {
      // ---- G(t+1) rebuild on the idle k0 slot; write frag tile to LDS ----
      const int tn = (t + 1 < NTS) ? (t + 1) : t;
      f32x4 uv = *(const f32x4*)&sU[tn][0];
      float gv[8];
      #pragma unroll
      for (int q = 0; q < 8; ++q)
        gv[q] = G0v[q] + uv[0]*Gcv[0][q] + uv[1]*Gcv[1][q] + uv[2]*Gcv[2][q] + uv[3]*Gcv[3][q];
      short8 Gh_, Gl_;
      pack8(gv, Gh_, Gl_);
      *(short8*)&sGh[fm*BST + fq*8] = Gh_;
      *(short8*)&sGl[fm*BST + fq*8] = Gl_;
    }
    // wv1-3: idle in phase 2
  }

  // ---- final coalesced pops flush (float4), 384-thread strided ----
  __syncthreads();
  for (int i4 = tid; i4 < NTS*DIM/4; i4 += 384) {
    int idx = i4 * 4;                            // idx = t*16 + d, d 4-aligned
    int tt = idx >> 4, dd = idx & 15;
    *(float4*)&g_out[tt*(BATCH*DIM) + b*DIM + dd] = *(const float4*)&sPops[idx];
  }
}

extern "C" void kernel_launch(void* const* d_in, const int* in_sizes, int n_in,
                              void* d_out, int out_size, void* d_ws, size_t ws_size,
                              hipStream_t stream) {
  (void)out_size; (void)d_ws; (void)ws_size;
  const void *P, *H0r, *H0i, *Hcr, *Hci, *Lr, *Li, *R0r, *R0i;
  int idx64 = -1;
  for (int q = 0; q < n_in; ++q) if (in_sizes[q] == 64) idx64 = q;
  if (idx64 == 6) {   // alphabetical fallback
    H0i = d_in[0]; H0r = d_in[1];
    Hci = d_in[2]; Hcr = d_in[3];
    Li  = d_in[4]; Lr  = d_in[5];
    P   = d_in[6];
    R0i = d_in[7]; R0r = d_in[8];
  } else {            // documented setup_inputs() dict order (R4-verified)
    P   = d_in[0];
    H0r = d_in[1]; H0i = d_in[2];
    Hcr = d_in[3]; Hci = d_in[4];
    Lr  = d_in[5]; Li  = d_in[6];
    R0r = d_in[7]; R0i = d_in[8];
  }
  lindblad_evolve<<<dim3(BATCH), dim3(384), 0, stream>>>(
      P, H0r, H0i, Hcr, Hci, Lr, Li, R0r, R0i, (float*)d_out);
}